// Round 2
// baseline (1616.177 us; speedup 1.0000x reference)
//
#include <hip/hip_runtime.h>
#include <stdint.h>

#define ROWS 4096
#define DIM 1024
#define VOCAB 32000
#define BM 128
#define BN 128
#define NTILES (VOCAB / BN)  // 250
#define NCHUNKS 32           // 32 row-blocks * 32 = 1024 blocks = 4/CU, all co-resident
#define SCALE 2048.0f        // keeps f16 lo-plane normal; argmax is scale-invariant

typedef float floatx4 __attribute__((ext_vector_type(4)));
typedef _Float16 f16x8 __attribute__((ext_vector_type(8)));
typedef _Float16 f16x4 __attribute__((ext_vector_type(4)));

__device__ __forceinline__ void load_lds16(const _Float16* g, _Float16* l) {
    __builtin_amdgcn_global_load_lds(
        (const __attribute__((address_space(1))) uint32_t*)g,
        (__attribute__((address_space(3))) uint32_t*)l, 16, 0, 0);
}

// ---- kernel 0 (fallback path only): zero the per-row argmax keys ----
__global__ void init_keys(unsigned long long* __restrict__ keys) {
    int i = blockIdx.x * 256 + threadIdx.x;
    if (i < ROWS) keys[i] = 0ull;
}

// ---- fused prep: keys init + A=emb+noise split + B=table split (f16 hi/lo planes) ----
__global__ void prep(const float* __restrict__ emb, const float* __restrict__ noi,
                     const float* __restrict__ table,
                     _Float16* __restrict__ Ah, _Float16* __restrict__ Al,
                     _Float16* __restrict__ Bh, _Float16* __restrict__ Bl,
                     unsigned long long* __restrict__ keys) {
    const int bid = blockIdx.x;
    const int ABLK = ROWS * DIM / 8 / 256;  // 2048
    if (bid < ABLK) {
        if (bid < ROWS / 256) keys[bid * 256 + threadIdx.x] = 0ull;
        size_t i = ((size_t)bid * 256 + threadIdx.x) * 8;
        floatx4 a = *(const floatx4*)(emb + i);
        floatx4 b = *(const floatx4*)(emb + i + 4);
        floatx4 c = *(const floatx4*)(noi + i);
        floatx4 d = *(const floatx4*)(noi + i + 4);
        f16x8 h, l;
#pragma unroll
        for (int j = 0; j < 4; j++) {
            float p = (a[j] + c[j]) * SCALE;
            _Float16 hh = (_Float16)p;
            h[j] = hh; l[j] = (_Float16)(p - (float)hh);
            float q = (b[j] + d[j]) * SCALE;
            _Float16 hq = (_Float16)q;
            h[4 + j] = hq; l[4 + j] = (_Float16)(q - (float)hq);
        }
        *(f16x8*)(Ah + i) = h;
        *(f16x8*)(Al + i) = l;
    } else {
        size_t i = ((size_t)(bid - ABLK) * 256 + threadIdx.x) * 8;
        floatx4 a = *(const floatx4*)(table + i);
        floatx4 b = *(const floatx4*)(table + i + 4);
        f16x8 h, l;
#pragma unroll
        for (int j = 0; j < 4; j++) {
            float p = a[j] * SCALE;
            _Float16 hh = (_Float16)p;
            h[j] = hh; l[j] = (_Float16)(p - (float)hh);
            float q = b[j] * SCALE;
            _Float16 hq = (_Float16)q;
            h[4 + j] = hq; l[4 + j] = (_Float16)(q - (float)hq);
        }
        *(f16x8*)(Bh + i) = h;
        *(f16x8*)(Bl + i) = l;
    }
}

// ---- main GEMM+argmax: single-buffer LDS (33.8 KB -> 4 blocks/CU), ----
// ---- conflict-free piece-major LDS layout (verified R1).           ----
// grid = 32 * NCHUNKS = 1024; block = 256 (4 waves, 2x2 wave grid). BK=32.
//
// LDS plane layout: 8 blocks of (16 rows x 32 f16) stored piece-major:
//   elem_off(block, row, piece) = block*512 + piece*128 + row*8
// global_load_lds writes lane l at +l*16B, so lane l fetches
//   row = blk*16 + (l&15), k-piece = (l>>4)   (per-lane global src is free).
// Fragment read for lane(quad,lq) is then base + lane*16B: a contiguous 1 KB
// ds_read_b128 per wave -> zero bank conflicts by construction.
// Latency hiding comes from 4 co-resident blocks/CU (16 waves at different
// K-loop phases), not from in-wave prefetch (R1 showed depth-1 prefetch at
// 2 blocks/CU is a net loss).
__global__ __launch_bounds__(256, 4) void gemm_argmax_pre(
    const _Float16* __restrict__ Ah, const _Float16* __restrict__ Al,
    const _Float16* __restrict__ Bh, const _Float16* __restrict__ Bl,
    unsigned long long* __restrict__ keys) {
    __shared__ __align__(16) _Float16 sAh[BM * 32];
    __shared__ __align__(16) _Float16 sAl[BM * 32];
    __shared__ __align__(16) _Float16 sBh[BN * 32];
    __shared__ __align__(16) _Float16 sBl[BN * 32];
    __shared__ unsigned long long redk[BM];

    const int tid = threadIdx.x;
    const int w = tid >> 6, lane = tid & 63;
    const int quad = lane >> 4, lq = lane & 15;
    const int rb = blockIdx.x / NCHUNKS, chunk = blockIdx.x % NCHUNKS;
    const int row0 = rb * BM;
    const int wmb = (w & 1) * 4, wnb = (w >> 1) * 4;  // 16-row block indices
    const int wm = wmb * 16, wn = wnb * 16;
    const int tstart = chunk * NTILES / NCHUNKS;
    const int tend = (chunk + 1) * NTILES / NCHUNKS;

    if (tid < BM) redk[tid] = 0ull;  // barriers intervene before use

    // runtime layout probe: c1 slot value = logical m, c2 = logical n
    union PF { f16x8 v; _Float16 s[8]; } fidx, fone;
#pragma unroll
    for (int j = 0; j < 8; j++) { fidx.s[j] = (_Float16)0.0f; fone.s[j] = (_Float16)0.0f; }
    if (quad == 0) { fidx.s[0] = (_Float16)(float)lq; fone.s[0] = (_Float16)1.0f; }
    floatx4 c1 = {0.f, 0.f, 0.f, 0.f}, c2 = {0.f, 0.f, 0.f, 0.f};
    c1 = __builtin_amdgcn_mfma_f32_16x16x32_f16(fidx.v, fone.v, c1, 0, 0, 0);
    c2 = __builtin_amdgcn_mfma_f32_16x16x32_f16(fone.v, fidx.v, c2, 0, 0, 0);
    int m_of[4], n_of[4];
#pragma unroll
    for (int r = 0; r < 4; r++) {
        m_of[r] = (int)(c1[r] + 0.5f);
        n_of[r] = (int)(c2[r] + 0.5f);
    }

    // wave -> plane assignment for staging (wave-uniform)
    const _Float16* gbase = (w == 0) ? (Ah + (size_t)row0 * DIM)
                        : (w == 1) ? (Al + (size_t)row0 * DIM)
                        : (w == 2) ? Bh : Bl;  // B base gets +n0*DIM per tile
    _Float16* ldst = (w == 0) ? sAh : (w == 1) ? sAl : (w == 2) ? sBh : sBl;
    // lane l sources row (l&15), k-piece (l>>4) of each 16-row block so the
    // linear LDS write lands piece-major
    const size_t g_lane = (size_t)(lane & 15) * DIM + (size_t)(lane >> 4) * 8;
    const int loff = quad * 128 + lq * 8;  // piece-major intra-block offset
    const bool isB = (w >= 2);

    float rmax[16];
    int ridx[16];
#pragma unroll
    for (int i = 0; i < 16; i++) { rmax[i] = -3.4e38f; ridx[i] = 0; }

    for (int t = tstart; t < tend; ++t) {
        const int n0 = t * BN;
        const _Float16* gsrc = gbase + (isB ? (size_t)t * BN * DIM : 0) + g_lane;
        floatx4 acc[4][4];
#pragma unroll
        for (int mi = 0; mi < 4; mi++)
#pragma unroll
            for (int ni = 0; ni < 4; ni++)
#pragma unroll
                for (int r = 0; r < 4; r++) acc[mi][ni][r] = 0.0f;

        for (int kt = 0; kt < DIM / 32; ++kt) {
            const int k0 = kt * 32;
            __syncthreads();  // previous step's LDS reads complete
            // each wave stages one full plane: 8 blocks of 16 rows x 32 f16
#pragma unroll
            for (int c = 0; c < 8; c++)
                load_lds16(gsrc + (size_t)(c * 16) * DIM + k0, ldst + c * 512);
            __syncthreads();  // staged data visible (compiler drains vmcnt)

            f16x8 ahf[4], alf[4];
#pragma unroll
            for (int i = 0; i < 4; i++) {
                ahf[i] = *(const f16x8*)(&sAh[(wmb + i) * 512 + loff]);
                alf[i] = *(const f16x8*)(&sAl[(wmb + i) * 512 + loff]);
            }
#pragma unroll
            for (int ni = 0; ni < 4; ni++) {
                f16x8 bh = *(const f16x8*)(&sBh[(wnb + ni) * 512 + loff]);
                f16x8 bl = *(const f16x8*)(&sBl[(wnb + ni) * 512 + loff]);
#pragma unroll
                for (int mi = 0; mi < 4; mi++) {
                    acc[mi][ni] = __builtin_amdgcn_mfma_f32_16x16x32_f16(
                        ahf[mi], bh, acc[mi][ni], 0, 0, 0);
                    acc[mi][ni] = __builtin_amdgcn_mfma_f32_16x16x32_f16(
                        ahf[mi], bl, acc[mi][ni], 0, 0, 0);
                    acc[mi][ni] = __builtin_amdgcn_mfma_f32_16x16x32_f16(
                        alf[mi], bh, acc[mi][ni], 0, 0, 0);
                }
            }
        }
        // fold this n-tile into per-row running argmax (probed layout)
#pragma unroll
        for (int mi = 0; mi < 4; mi++)
#pragma unroll
            for (int ni = 0; ni < 4; ni++)
#pragma unroll
                for (int r = 0; r < 4; r++) {
                    float v = acc[mi][ni][r];
                    int col = n0 + wn + ni * 16 + n_of[r];
                    int s = mi * 4 + r;
                    if (v > rmax[s] || (v == rmax[s] && col < ridx[s])) {
                        rmax[s] = v;
                        ridx[s] = col;
                    }
                }
    }

    // reduce: LDS atomicMax keyed by probed row, then one global atomic per row
#pragma unroll
    for (int s = 0; s < 16; ++s) {
        int mi = s >> 2, r = s & 3;
        int rowl = wm + mi * 16 + m_of[r];
        union { float f; uint32_t i; } u;
        u.f = rmax[s];
        uint32_t ord = (u.i & 0x80000000u) ? ~u.i : (u.i | 0x80000000u);
        unsigned long long key =
            ((unsigned long long)ord << 32) | (uint32_t)(~(uint32_t)ridx[s]);
        atomicMax(&redk[rowl], key);
    }
    __syncthreads();
    if (tid < BM) atomicMax(&keys[row0 + tid], redk[tid]);
}

// ================== fallback path (verified): in-kernel split ==================
#define BKF 64
#define LDKF 72
#define TILES_PER_WGF 10
#define NCHUNKSF 25

__global__ __launch_bounds__(256, 2) void gemm_argmax_fused(
    const float* __restrict__ emb, const float* __restrict__ noi,
    const float* __restrict__ table, unsigned long long* __restrict__ keys) {
    __shared__ __align__(16) _Float16 Ah[BM * LDKF];
    __shared__ __align__(16) _Float16 Al[BM * LDKF];
    __shared__ __align__(16) _Float16 Bh[BN * LDKF];
    __shared__ __align__(16) _Float16 Bl[BN * LDKF];
    __shared__ unsigned long long redk[BM];

    const int tid = threadIdx.x;
    const int wave = tid >> 6, lane = tid & 63;
    const int quad = lane >> 4, lq = lane & 15;
    const int rb = blockIdx.x / NCHUNKSF, chunk = blockIdx.x % NCHUNKSF;
    const int row0 = rb * BM;
    const int wm = (wave & 1) * 64, wn = (wave >> 1) * 64;

    if (tid < BM) redk[tid] = 0ull;

    union PF { f16x8 v; _Float16 s[8]; } fidx, fone;
#pragma unroll
    for (int j = 0; j < 8; j++) { fidx.s[j] = (_Float16)0.0f; fone.s[j] = (_Float16)0.0f; }
    if (quad == 0) { fidx.s[0] = (_Float16)(float)lq; fone.s[0] = (_Float16)1.0f; }
    floatx4 c1 = {0.f, 0.f, 0.f, 0.f}, c2 = {0.f, 0.f, 0.f, 0.f};
    c1 = __builtin_amdgcn_mfma_f32_16x16x32_f16(fidx.v, fone.v, c1, 0, 0, 0);
    c2 = __builtin_amdgcn_mfma_f32_16x16x32_f16(fone.v, fidx.v, c2, 0, 0, 0);
    int m_of[4], n_of[4];
#pragma unroll
    for (int r = 0; r < 4; r++) {
        m_of[r] = (int)(c1[r] + 0.5f);
        n_of[r] = (int)(c2[r] + 0.5f);
    }

    float rmax[16];
    int ridx[16];
#pragma unroll
    for (int i = 0; i < 16; i++) { rmax[i] = -3.4e38f; ridx[i] = 0; }

    for (int t = 0; t < TILES_PER_WGF; ++t) {
        const int n0 = (chunk * TILES_PER_WGF + t) * BN;
        floatx4 acc[4][4];
#pragma unroll
        for (int mi = 0; mi < 4; mi++)
#pragma unroll
            for (int ni = 0; ni < 4; ni++)
#pragma unroll
                for (int r = 0; r < 4; r++) acc[mi][ni][r] = 0.0f;

        for (int kt = 0; kt < DIM / BKF; ++kt) {
            const int k0 = kt * BKF;
            __syncthreads();
#pragma unroll
            for (int i = 0; i < 8; i++) {
                int c = i * 256 + tid;
                int r = c >> 4, q = c & 15;
                floatx4 e = *(const floatx4*)(emb + (size_t)(row0 + r) * DIM + k0 + q * 4);
                floatx4 n = *(const floatx4*)(noi + (size_t)(row0 + r) * DIM + k0 + q * 4);
                floatx4 b = *(const floatx4*)(table + (size_t)(n0 + r) * DIM + k0 + q * 4);
                f16x4 ah, al, bh, bl;
#pragma unroll
                for (int j = 0; j < 4; j++) {
                    float pa = (e[j] + n[j]) * SCALE;
                    _Float16 h = (_Float16)pa;
                    ah[j] = h;
                    al[j] = (_Float16)(pa - (float)h);
                    float pb = b[j] * SCALE;
                    _Float16 hb = (_Float16)pb;
                    bh[j] = hb;
                    bl[j] = (_Float16)(pb - (float)hb);
                }
                *(f16x4*)(Ah + r * LDKF + q * 4) = ah;
                *(f16x4*)(Al + r * LDKF + q * 4) = al;
                *(f16x4*)(Bh + r * LDKF + q * 4) = bh;
                *(f16x4*)(Bl + r * LDKF + q * 4) = bl;
            }
            __syncthreads();
#pragma unroll
            for (int ks = 0; ks < BKF; ks += 32) {
                f16x8 bhf[4], blf[4], ahf[4], alf[4];
#pragma unroll
                for (int i = 0; i < 4; i++) {
                    bhf[i] = *(const f16x8*)(Bh + (wn + i * 16 + lq) * LDKF + ks + quad * 8);
                    blf[i] = *(const f16x8*)(Bl + (wn + i * 16 + lq) * LDKF + ks + quad * 8);
                    ahf[i] = *(const f16x8*)(Ah + (wm + i * 16 + lq) * LDKF + ks + quad * 8);
                    alf[i] = *(const f16x8*)(Al + (wm + i * 16 + lq) * LDKF + ks + quad * 8);
                }
#pragma unroll
                for (int mi = 0; mi < 4; mi++)
#pragma unroll
                    for (int ni = 0; ni < 4; ni++) {
                        acc[mi][ni] = __builtin_amdgcn_mfma_f32_16x16x32_f16(
                            ahf[mi], bhf[ni], acc[mi][ni], 0, 0, 0);
                        acc[mi][ni] = __builtin_amdgcn_mfma_f32_16x16x32_f16(
                            ahf[mi], blf[ni], acc[mi][ni], 0, 0, 0);
                        acc[mi][ni] = __builtin_amdgcn_mfma_f32_16x16x32_f16(
                            alf[mi], bhf[ni], acc[mi][ni], 0, 0, 0);
                    }
            }
        }
#pragma unroll
        for (int mi = 0; mi < 4; mi++)
#pragma unroll
            for (int ni = 0; ni < 4; ni++)
#pragma unroll
                for (int r = 0; r < 4; r++) {
                    float v = acc[mi][ni][r];
                    int col = n0 + wn + ni * 16 + n_of[r];
                    int s = mi * 4 + r;
                    if (v > rmax[s] || (v == rmax[s] && col < ridx[s])) {
                        rmax[s] = v;
                        ridx[s] = col;
                    }
                }
    }

#pragma unroll
    for (int s = 0; s < 16; ++s) {
        int mi = s >> 2, r = s & 3;
        int rowl = wm + mi * 16 + m_of[r];
        union { float f; uint32_t i; } u;
        u.f = rmax[s];
        uint32_t ord = (u.i & 0x80000000u) ? ~u.i : (u.i | 0x80000000u);
        unsigned long long key =
            ((unsigned long long)ord << 32) | (uint32_t)(~(uint32_t)ridx[s]);
        atomicMax(&redk[rowl], key);
    }
    __syncthreads();
    if (tid < BM) atomicMax(&keys[row0 + tid], redk[tid]);
}

// ---- gather winning table rows (f32) to output ----
__global__ void gather_kernel(const unsigned long long* __restrict__ keys,
                              const float* __restrict__ table,
                              float* __restrict__ out) {
    int row = blockIdx.x;
    unsigned long long key = keys[row];
    uint32_t ix = ~(uint32_t)(key & 0xFFFFFFFFull);
    const floatx4* src = (const floatx4*)(table + (size_t)ix * DIM);
    floatx4* dst = (floatx4*)(out + (size_t)row * DIM);
    dst[threadIdx.x] = src[threadIdx.x];  // 256 * 16B = 4 KB row
}

extern "C" void kernel_launch(void* const* d_in, const int* in_sizes, int n_in,
                              void* d_out, int out_size, void* d_ws, size_t ws_size,
                              hipStream_t stream) {
    (void)in_sizes; (void)n_in; (void)out_size;
    const float* emb = (const float*)d_in[0];
    const float* table = (const float*)d_in[1];
    const float* noi = (const float*)d_in[2];
    float* out = (float*)d_out;

    uint8_t* ws = (uint8_t*)d_ws;
    unsigned long long* keys = (unsigned long long*)ws;
    const size_t keysB = (size_t)ROWS * 8;
    const size_t aB = (size_t)ROWS * DIM * 2;    // 8.39 MB per A plane
    const size_t bB = (size_t)VOCAB * DIM * 2;   // 65.5 MB per B plane
    const size_t need = keysB + 2 * aB + 2 * bB; // ~141 MB

    if (ws_size >= need) {
        _Float16* Ah = (_Float16*)(ws + keysB);
        _Float16* Al = (_Float16*)(ws + keysB + aB);
        _Float16* Bh = (_Float16*)(ws + keysB + 2 * aB);
        _Float16* Bl = (_Float16*)(ws + keysB + 2 * aB + bB);
        const int ablk = ROWS * DIM / 8 / 256;       // 2048
        const int bblk = VOCAB * DIM / 8 / 256;      // 16000
        prep<<<ablk + bblk, 256, 0, stream>>>(emb, noi, table, Ah, Al, Bh, Bl, keys);
        gemm_argmax_pre<<<(ROWS / BM) * NCHUNKS, 256, 0, stream>>>(Ah, Al, Bh, Bl, keys);
    } else {
        init_keys<<<ROWS / 256, 256, 0, stream>>>(keys);
        gemm_argmax_fused<<<(ROWS / BM) * NCHUNKSF, 256, 0, stream>>>(emb, noi, table, keys);
    }
    gather_kernel<<<ROWS, 256, 0, stream>>>(keys, table, out);
}

// Round 3
// 1326.831 us; speedup vs baseline: 1.2181x; 1.2181x over previous
//
#include <hip/hip_runtime.h>
#include <stdint.h>

#define ROWS 4096
#define DIM 1024
#define VOCAB 32000
#define BM 128
#define BN 128
#define NTILES (VOCAB / BN)  // 250
#define NCHUNKS 32           // 32 row-blocks * 32 = 1024 blocks = 4/CU, all co-resident
#define SCALE 2048.0f        // keeps f16 lo-plane normal; argmax is scale-invariant

typedef float floatx4 __attribute__((ext_vector_type(4)));
typedef _Float16 f16x8 __attribute__((ext_vector_type(8)));
typedef _Float16 f16x4 __attribute__((ext_vector_type(4)));

__device__ __forceinline__ void load_lds16(const _Float16* g, _Float16* l) {
    __builtin_amdgcn_global_load_lds(
        (const __attribute__((address_space(1))) uint32_t*)g,
        (__attribute__((address_space(3))) uint32_t*)l, 16, 0, 0);
}

// ---- kernel 0 (fallback path only): zero the per-row argmax keys ----
__global__ void init_keys(unsigned long long* __restrict__ keys) {
    int i = blockIdx.x * 256 + threadIdx.x;
    if (i < ROWS) keys[i] = 0ull;
}

// ---- fused prep: keys init + A=emb+noise split + B=table split (f16 hi/lo planes) ----
__global__ void prep(const float* __restrict__ emb, const float* __restrict__ noi,
                     const float* __restrict__ table,
                     _Float16* __restrict__ Ah, _Float16* __restrict__ Al,
                     _Float16* __restrict__ Bh, _Float16* __restrict__ Bl,
                     unsigned long long* __restrict__ keys) {
    const int bid = blockIdx.x;
    const int ABLK = ROWS * DIM / 8 / 256;  // 2048
    if (bid < ABLK) {
        if (bid < ROWS / 256) keys[bid * 256 + threadIdx.x] = 0ull;
        size_t i = ((size_t)bid * 256 + threadIdx.x) * 8;
        floatx4 a = *(const floatx4*)(emb + i);
        floatx4 b = *(const floatx4*)(emb + i + 4);
        floatx4 c = *(const floatx4*)(noi + i);
        floatx4 d = *(const floatx4*)(noi + i + 4);
        f16x8 h, l;
#pragma unroll
        for (int j = 0; j < 4; j++) {
            float p = (a[j] + c[j]) * SCALE;
            _Float16 hh = (_Float16)p;
            h[j] = hh; l[j] = (_Float16)(p - (float)hh);
            float q = (b[j] + d[j]) * SCALE;
            _Float16 hq = (_Float16)q;
            h[4 + j] = hq; l[4 + j] = (_Float16)(q - (float)hq);
        }
        *(f16x8*)(Ah + i) = h;
        *(f16x8*)(Al + i) = l;
    } else {
        size_t i = ((size_t)(bid - ABLK) * 256 + threadIdx.x) * 8;
        floatx4 a = *(const floatx4*)(table + i);
        floatx4 b = *(const floatx4*)(table + i + 4);
        f16x8 h, l;
#pragma unroll
        for (int j = 0; j < 4; j++) {
            float p = a[j] * SCALE;
            _Float16 hh = (_Float16)p;
            h[j] = hh; l[j] = (_Float16)(p - (float)hh);
            float q = b[j] * SCALE;
            _Float16 hq = (_Float16)q;
            h[4 + j] = hq; l[4 + j] = (_Float16)(q - (float)hq);
        }
        *(f16x8*)(Bh + i) = h;
        *(f16x8*)(Bl + i) = l;
    }
}

// ---- main GEMM+argmax: single-buffer LDS (33.8 KB), conflict-free ----
// ---- piece-major LDS layout (verified R1).                        ----
// grid = 32 * NCHUNKS = 1024; block = 256 (4 waves, 2x2 wave grid). BK=32.
//
// __launch_bounds__(256, 3): caps VGPR at the 128 tier; compiler lands
// ~84-88 VGPR (R0/R1 evidence), which itself permits 4 waves/SIMD -> with
// 33.8 KB LDS, 4 blocks/CU are co-resident at grid=1024. Do NOT use
// min-waves=4: R2 showed it forces the 64-VGPR tier and spills the
// accumulators (WRITE_SIZE 512 KB -> 1.18 GB, MfmaUtil 33 -> 23%).
//
// LDS plane layout: 8 blocks of (16 rows x 32 f16) stored piece-major:
//   elem_off(block, row, piece) = block*512 + piece*128 + row*8
// global_load_lds writes lane l at +l*16B, so lane l fetches
//   row = blk*16 + (l&15), k-piece = (l>>4)   (per-lane global src is free).
// Fragment read for lane(quad,lq) is then base + lane*16B: a contiguous 1 KB
// ds_read_b128 per wave -> zero bank conflicts by construction.
// Latency hiding comes from 4 co-resident blocks/CU at different K-loop
// phases (R1 showed depth-1 in-wave prefetch at 2 blocks/CU is a net loss).
__global__ __launch_bounds__(256, 3) void gemm_argmax_pre(
    const _Float16* __restrict__ Ah, const _Float16* __restrict__ Al,
    const _Float16* __restrict__ Bh, const _Float16* __restrict__ Bl,
    unsigned long long* __restrict__ keys) {
    __shared__ __align__(16) _Float16 sAh[BM * 32];
    __shared__ __align__(16) _Float16 sAl[BM * 32];
    __shared__ __align__(16) _Float16 sBh[BN * 32];
    __shared__ __align__(16) _Float16 sBl[BN * 32];
    __shared__ unsigned long long redk[BM];

    const int tid = threadIdx.x;
    const int w = tid >> 6, lane = tid & 63;
    const int quad = lane >> 4, lq = lane & 15;
    const int rb = blockIdx.x / NCHUNKS, chunk = blockIdx.x % NCHUNKS;
    const int row0 = rb * BM;
    const int wmb = (w & 1) * 4, wnb = (w >> 1) * 4;  // 16-row block indices
    const int wm = wmb * 16, wn = wnb * 16;
    const int tstart = chunk * NTILES / NCHUNKS;
    const int tend = (chunk + 1) * NTILES / NCHUNKS;

    if (tid < BM) redk[tid] = 0ull;  // barriers intervene before use

    // runtime layout probe: c1 slot value = logical m, c2 = logical n
    union PF { f16x8 v; _Float16 s[8]; } fidx, fone;
#pragma unroll
    for (int j = 0; j < 8; j++) { fidx.s[j] = (_Float16)0.0f; fone.s[j] = (_Float16)0.0f; }
    if (quad == 0) { fidx.s[0] = (_Float16)(float)lq; fone.s[0] = (_Float16)1.0f; }
    floatx4 c1 = {0.f, 0.f, 0.f, 0.f}, c2 = {0.f, 0.f, 0.f, 0.f};
    c1 = __builtin_amdgcn_mfma_f32_16x16x32_f16(fidx.v, fone.v, c1, 0, 0, 0);
    c2 = __builtin_amdgcn_mfma_f32_16x16x32_f16(fone.v, fidx.v, c2, 0, 0, 0);
    int m_of[4], n_of[4];
#pragma unroll
    for (int r = 0; r < 4; r++) {
        m_of[r] = (int)(c1[r] + 0.5f);
        n_of[r] = (int)(c2[r] + 0.5f);
    }

    // wave -> plane assignment for staging (wave-uniform)
    const _Float16* gbase = (w == 0) ? (Ah + (size_t)row0 * DIM)
                        : (w == 1) ? (Al + (size_t)row0 * DIM)
                        : (w == 2) ? Bh : Bl;  // B base gets +n0*DIM per tile
    _Float16* ldst = (w == 0) ? sAh : (w == 1) ? sAl : (w == 2) ? sBh : sBl;
    // lane l sources row (l&15), k-piece (l>>4) of each 16-row block so the
    // linear LDS write lands piece-major
    const size_t g_lane = (size_t)(lane & 15) * DIM + (size_t)(lane >> 4) * 8;
    const int loff = quad * 128 + lq * 8;  // piece-major intra-block offset
    const bool isB = (w >= 2);

    float rmax[16];
    int ridx[16];
#pragma unroll
    for (int i = 0; i < 16; i++) { rmax[i] = -3.4e38f; ridx[i] = 0; }

    for (int t = tstart; t < tend; ++t) {
        const int n0 = t * BN;
        const _Float16* gsrc = gbase + (isB ? (size_t)t * BN * DIM : 0) + g_lane;
        floatx4 acc[4][4];
#pragma unroll
        for (int mi = 0; mi < 4; mi++)
#pragma unroll
            for (int ni = 0; ni < 4; ni++)
#pragma unroll
                for (int r = 0; r < 4; r++) acc[mi][ni][r] = 0.0f;

        for (int kt = 0; kt < DIM / 32; ++kt) {
            const int k0 = kt * 32;
            __syncthreads();  // previous step's LDS reads complete
            // each wave stages one full plane: 8 blocks of 16 rows x 32 f16
#pragma unroll
            for (int c = 0; c < 8; c++)
                load_lds16(gsrc + (size_t)(c * 16) * DIM + k0, ldst + c * 512);
            __syncthreads();  // staged data visible (compiler drains vmcnt)

            f16x8 ahf[4], alf[4];
#pragma unroll
            for (int i = 0; i < 4; i++) {
                ahf[i] = *(const f16x8*)(&sAh[(wmb + i) * 512 + loff]);
                alf[i] = *(const f16x8*)(&sAl[(wmb + i) * 512 + loff]);
            }
#pragma unroll
            for (int ni = 0; ni < 4; ni++) {
                f16x8 bh = *(const f16x8*)(&sBh[(wnb + ni) * 512 + loff]);
                f16x8 bl = *(const f16x8*)(&sBl[(wnb + ni) * 512 + loff]);
#pragma unroll
                for (int mi = 0; mi < 4; mi++) {
                    acc[mi][ni] = __builtin_amdgcn_mfma_f32_16x16x32_f16(
                        ahf[mi], bh, acc[mi][ni], 0, 0, 0);
                    acc[mi][ni] = __builtin_amdgcn_mfma_f32_16x16x32_f16(
                        ahf[mi], bl, acc[mi][ni], 0, 0, 0);
                    acc[mi][ni] = __builtin_amdgcn_mfma_f32_16x16x32_f16(
                        alf[mi], bh, acc[mi][ni], 0, 0, 0);
                }
            }
        }
        // fold this n-tile into per-row running argmax (probed layout)
#pragma unroll
        for (int mi = 0; mi < 4; mi++)
#pragma unroll
            for (int ni = 0; ni < 4; ni++)
#pragma unroll
                for (int r = 0; r < 4; r++) {
                    float v = acc[mi][ni][r];
                    int col = n0 + wn + ni * 16 + n_of[r];
                    int s = mi * 4 + r;
                    if (v > rmax[s] || (v == rmax[s] && col < ridx[s])) {
                        rmax[s] = v;
                        ridx[s] = col;
                    }
                }
    }

    // reduce: LDS atomicMax keyed by probed row, then one global atomic per row
#pragma unroll
    for (int s = 0; s < 16; ++s) {
        int mi = s >> 2, r = s & 3;
        int rowl = wm + mi * 16 + m_of[r];
        union { float f; uint32_t i; } u;
        u.f = rmax[s];
        uint32_t ord = (u.i & 0x80000000u) ? ~u.i : (u.i | 0x80000000u);
        unsigned long long key =
            ((unsigned long long)ord << 32) | (uint32_t)(~(uint32_t)ridx[s]);
        atomicMax(&redk[rowl], key);
    }
    __syncthreads();
    if (tid < BM) atomicMax(&keys[row0 + tid], redk[tid]);
}

// ================== fallback path (verified): in-kernel split ==================
#define BKF 64
#define LDKF 72
#define TILES_PER_WGF 10
#define NCHUNKSF 25

__global__ __launch_bounds__(256, 2) void gemm_argmax_fused(
    const float* __restrict__ emb, const float* __restrict__ noi,
    const float* __restrict__ table, unsigned long long* __restrict__ keys) {
    __shared__ __align__(16) _Float16 Ah[BM * LDKF];
    __shared__ __align__(16) _Float16 Al[BM * LDKF];
    __shared__ __align__(16) _Float16 Bh[BN * LDKF];
    __shared__ __align__(16) _Float16 Bl[BN * LDKF];
    __shared__ unsigned long long redk[BM];

    const int tid = threadIdx.x;
    const int wave = tid >> 6, lane = tid & 63;
    const int quad = lane >> 4, lq = lane & 15;
    const int rb = blockIdx.x / NCHUNKSF, chunk = blockIdx.x % NCHUNKSF;
    const int row0 = rb * BM;
    const int wm = (wave & 1) * 64, wn = (wave >> 1) * 64;

    if (tid < BM) redk[tid] = 0ull;

    union PF { f16x8 v; _Float16 s[8]; } fidx, fone;
#pragma unroll
    for (int j = 0; j < 8; j++) { fidx.s[j] = (_Float16)0.0f; fone.s[j] = (_Float16)0.0f; }
    if (quad == 0) { fidx.s[0] = (_Float16)(float)lq; fone.s[0] = (_Float16)1.0f; }
    floatx4 c1 = {0.f, 0.f, 0.f, 0.f}, c2 = {0.f, 0.f, 0.f, 0.f};
    c1 = __builtin_amdgcn_mfma_f32_16x16x32_f16(fidx.v, fone.v, c1, 0, 0, 0);
    c2 = __builtin_amdgcn_mfma_f32_16x16x32_f16(fone.v, fidx.v, c2, 0, 0, 0);
    int m_of[4], n_of[4];
#pragma unroll
    for (int r = 0; r < 4; r++) {
        m_of[r] = (int)(c1[r] + 0.5f);
        n_of[r] = (int)(c2[r] + 0.5f);
    }

    float rmax[16];
    int ridx[16];
#pragma unroll
    for (int i = 0; i < 16; i++) { rmax[i] = -3.4e38f; ridx[i] = 0; }

    for (int t = 0; t < TILES_PER_WGF; ++t) {
        const int n0 = (chunk * TILES_PER_WGF + t) * BN;
        floatx4 acc[4][4];
#pragma unroll
        for (int mi = 0; mi < 4; mi++)
#pragma unroll
            for (int ni = 0; ni < 4; ni++)
#pragma unroll
                for (int r = 0; r < 4; r++) acc[mi][ni][r] = 0.0f;

        for (int kt = 0; kt < DIM / BKF; ++kt) {
            const int k0 = kt * BKF;
            __syncthreads();
#pragma unroll
            for (int i = 0; i < 8; i++) {
                int c = i * 256 + tid;
                int r = c >> 4, q = c & 15;
                floatx4 e = *(const floatx4*)(emb + (size_t)(row0 + r) * DIM + k0 + q * 4);
                floatx4 n = *(const floatx4*)(noi + (size_t)(row0 + r) * DIM + k0 + q * 4);
                floatx4 b = *(const floatx4*)(table + (size_t)(n0 + r) * DIM + k0 + q * 4);
                f16x4 ah, al, bh, bl;
#pragma unroll
                for (int j = 0; j < 4; j++) {
                    float pa = (e[j] + n[j]) * SCALE;
                    _Float16 h = (_Float16)pa;
                    ah[j] = h;
                    al[j] = (_Float16)(pa - (float)h);
                    float pb = b[j] * SCALE;
                    _Float16 hb = (_Float16)pb;
                    bh[j] = hb;
                    bl[j] = (_Float16)(pb - (float)hb);
                }
                *(f16x4*)(Ah + r * LDKF + q * 4) = ah;
                *(f16x4*)(Al + r * LDKF + q * 4) = al;
                *(f16x4*)(Bh + r * LDKF + q * 4) = bh;
                *(f16x4*)(Bl + r * LDKF + q * 4) = bl;
            }
            __syncthreads();
#pragma unroll
            for (int ks = 0; ks < BKF; ks += 32) {
                f16x8 bhf[4], blf[4], ahf[4], alf[4];
#pragma unroll
                for (int i = 0; i < 4; i++) {
                    bhf[i] = *(const f16x8*)(Bh + (wn + i * 16 + lq) * LDKF + ks + quad * 8);
                    blf[i] = *(const f16x8*)(Bl + (wn + i * 16 + lq) * LDKF + ks + quad * 8);
                    ahf[i] = *(const f16x8*)(Ah + (wm + i * 16 + lq) * LDKF + ks + quad * 8);
                    alf[i] = *(const f16x8*)(Al + (wm + i * 16 + lq) * LDKF + ks + quad * 8);
                }
#pragma unroll
                for (int mi = 0; mi < 4; mi++)
#pragma unroll
                    for (int ni = 0; ni < 4; ni++) {
                        acc[mi][ni] = __builtin_amdgcn_mfma_f32_16x16x32_f16(
                            ahf[mi], bhf[ni], acc[mi][ni], 0, 0, 0);
                        acc[mi][ni] = __builtin_amdgcn_mfma_f32_16x16x32_f16(
                            ahf[mi], blf[ni], acc[mi][ni], 0, 0, 0);
                        acc[mi][ni] = __builtin_amdgcn_mfma_f32_16x16x32_f16(
                            alf[mi], bhf[ni], acc[mi][ni], 0, 0, 0);
                    }
            }
        }
#pragma unroll
        for (int mi = 0; mi < 4; mi++)
#pragma unroll
            for (int ni = 0; ni < 4; ni++)
#pragma unroll
                for (int r = 0; r < 4; r++) {
                    float v = acc[mi][ni][r];
                    int col = n0 + wn + ni * 16 + n_of[r];
                    int s = mi * 4 + r;
                    if (v > rmax[s] || (v == rmax[s] && col < ridx[s])) {
                        rmax[s] = v;
                        ridx[s] = col;
                    }
                }
    }

#pragma unroll
    for (int s = 0; s < 16; ++s) {
        int mi = s >> 2, r = s & 3;
        int rowl = wm + mi * 16 + m_of[r];
        union { float f; uint32_t i; } u;
        u.f = rmax[s];
        uint32_t ord = (u.i & 0x80000000u) ? ~u.i : (u.i | 0x80000000u);
        unsigned long long key =
            ((unsigned long long)ord << 32) | (uint32_t)(~(uint32_t)ridx[s]);
        atomicMax(&redk[rowl], key);
    }
    __syncthreads();
    if (tid < BM) atomicMax(&keys[row0 + tid], redk[tid]);
}

// ---- gather winning table rows (f32) to output ----
__global__ void gather_kernel(const unsigned long long* __restrict__ keys,
                              const float* __restrict__ table,
                              float* __restrict__ out) {
    int row = blockIdx.x;
    unsigned long long key = keys[row];
    uint32_t ix = ~(uint32_t)(key & 0xFFFFFFFFull);
    const floatx4* src = (const floatx4*)(table + (size_t)ix * DIM);
    floatx4* dst = (floatx4*)(out + (size_t)row * DIM);
    dst[threadIdx.x] = src[threadIdx.x];  // 256 * 16B = 4 KB row
}

extern "C" void kernel_launch(void* const* d_in, const int* in_sizes, int n_in,
                              void* d_out, int out_size, void* d_ws, size_t ws_size,
                              hipStream_t stream) {
    (void)in_sizes; (void)n_in; (void)out_size;
    const float* emb = (const float*)d_in[0];
    const float* table = (const float*)d_in[1];
    const float* noi = (const float*)d_in[2];
    float* out = (float*)d_out;

    uint8_t* ws = (uint8_t*)d_ws;
    unsigned long long* keys = (unsigned long long*)ws;
    const size_t keysB = (size_t)ROWS * 8;
    const size_t aB = (size_t)ROWS * DIM * 2;    // 8.39 MB per A plane
    const size_t bB = (size_t)VOCAB * DIM * 2;   // 65.5 MB per B plane
    const size_t need = keysB + 2 * aB + 2 * bB; // ~141 MB

    if (ws_size >= need) {
        _Float16* Ah = (_Float16*)(ws + keysB);
        _Float16* Al = (_Float16*)(ws + keysB + aB);
        _Float16* Bh = (_Float16*)(ws + keysB + 2 * aB);
        _Float16* Bl = (_Float16*)(ws + keysB + 2 * aB + bB);
        const int ablk = ROWS * DIM / 8 / 256;       // 2048
        const int bblk = VOCAB * DIM / 8 / 256;      // 16000
        prep<<<ablk + bblk, 256, 0, stream>>>(emb, noi, table, Ah, Al, Bh, Bl, keys);
        gemm_argmax_pre<<<(ROWS / BM) * NCHUNKS, 256, 0, stream>>>(Ah, Al, Bh, Bl, keys);
    } else {
        init_keys<<<ROWS / 256, 256, 0, stream>>>(keys);
        gemm_argmax_fused<<<(ROWS / BM) * NCHUNKSF, 256, 0, stream>>>(emb, noi, table, keys);
    }
    gather_kernel<<<ROWS, 256, 0, stream>>>(keys, table, out);
}

// Round 4
// 1292.647 us; speedup vs baseline: 1.2503x; 1.0264x over previous
//
#include <hip/hip_runtime.h>
#include <stdint.h>

#define ROWS 4096
#define DIM 1024
#define VOCAB 32000
#define BM 128
#define BN 128
#define NTILES (VOCAB / BN)  // 250
#define NCHUNKS 24           // 32 row-blocks * 24 = 768 blocks = 3/CU co-resident
                             // (R3 evidence: 4/CU never materializes; grid 1024
                             //  leaves a 1-block/CU tail and halves MfmaUtil)
#define SCALE 2048.0f        // keeps f16 lo-plane normal; argmax is scale-invariant

typedef float floatx4 __attribute__((ext_vector_type(4)));
typedef _Float16 f16x8 __attribute__((ext_vector_type(8)));
typedef _Float16 f16x4 __attribute__((ext_vector_type(4)));

__device__ __forceinline__ void load_lds16(const _Float16* g, _Float16* l) {
    __builtin_amdgcn_global_load_lds(
        (const __attribute__((address_space(1))) uint32_t*)g,
        (__attribute__((address_space(3))) uint32_t*)l, 16, 0, 0);
}

// ---- kernel 0 (fallback path only): zero the per-row argmax keys ----
__global__ void init_keys(unsigned long long* __restrict__ keys) {
    int i = blockIdx.x * 256 + threadIdx.x;
    if (i < ROWS) keys[i] = 0ull;
}

// ---- fused prep: keys init + A=emb+noise split + B=table split (f16 hi/lo planes) ----
__global__ void prep(const float* __restrict__ emb, const float* __restrict__ noi,
                     const float* __restrict__ table,
                     _Float16* __restrict__ Ah, _Float16* __restrict__ Al,
                     _Float16* __restrict__ Bh, _Float16* __restrict__ Bl,
                     unsigned long long* __restrict__ keys) {
    const int bid = blockIdx.x;
    const int ABLK = ROWS * DIM / 8 / 256;  // 2048
    if (bid < ABLK) {
        if (bid < ROWS / 256) keys[bid * 256 + threadIdx.x] = 0ull;
        size_t i = ((size_t)bid * 256 + threadIdx.x) * 8;
        floatx4 a = *(const floatx4*)(emb + i);
        floatx4 b = *(const floatx4*)(emb + i + 4);
        floatx4 c = *(const floatx4*)(noi + i);
        floatx4 d = *(const floatx4*)(noi + i + 4);
        f16x8 h, l;
#pragma unroll
        for (int j = 0; j < 4; j++) {
            float p = (a[j] + c[j]) * SCALE;
            _Float16 hh = (_Float16)p;
            h[j] = hh; l[j] = (_Float16)(p - (float)hh);
            float q = (b[j] + d[j]) * SCALE;
            _Float16 hq = (_Float16)q;
            h[4 + j] = hq; l[4 + j] = (_Float16)(q - (float)hq);
        }
        *(f16x8*)(Ah + i) = h;
        *(f16x8*)(Al + i) = l;
    } else {
        size_t i = ((size_t)(bid - ABLK) * 256 + threadIdx.x) * 8;
        floatx4 a = *(const floatx4*)(table + i);
        floatx4 b = *(const floatx4*)(table + i + 4);
        f16x8 h, l;
#pragma unroll
        for (int j = 0; j < 4; j++) {
            float p = a[j] * SCALE;
            _Float16 hh = (_Float16)p;
            h[j] = hh; l[j] = (_Float16)(p - (float)hh);
            float q = b[j] * SCALE;
            _Float16 hq = (_Float16)q;
            h[4 + j] = hq; l[4 + j] = (_Float16)(q - (float)hq);
        }
        *(f16x8*)(Bh + i) = h;
        *(f16x8*)(Bl + i) = l;
    }
}

// ---- main GEMM+argmax: R0's exact schedule/occupancy operating point ----
// ---- (grid 768 = 3/CU, single-buffer, lb(256,3)) + piece-major LDS.  ----
// grid = 32 * NCHUNKS = 768; block = 256 (4 waves, 2x2 wave grid). BK=32.
//
// __launch_bounds__(256, 3): compiler lands ~84 VGPR (no spill). Do NOT use
// min-waves=4: R2 showed it forces the 64-VGPR tier and spills accumulators
// (WRITE_SIZE 512 KB -> 1.18 GB). Do NOT exceed 3 blocks/CU of grid pressure:
// R3 showed the 4th block never becomes resident (occ 24%, MfmaUtil 25%).
//
// LDS plane layout: 8 blocks of (16 rows x 32 f16) stored piece-major:
//   elem_off(block, row, piece) = block*512 + piece*128 + row*8
// global_load_lds writes lane l at +l*16B, so lane l fetches
//   row = blk*16 + (l&15), k-piece = (l>>4)   (per-lane global src is free).
// Fragment read for lane(quad,lq) is then base + lane*16B: a contiguous 1 KB
// ds_read_b128 per wave -> zero bank conflicts by construction
// (verified R1/R3: SQ_LDS_BANK_CONFLICT 6.85e7 -> 3.9e6).
__global__ __launch_bounds__(256, 3) void gemm_argmax_pre(
    const _Float16* __restrict__ Ah, const _Float16* __restrict__ Al,
    const _Float16* __restrict__ Bh, const _Float16* __restrict__ Bl,
    unsigned long long* __restrict__ keys) {
    __shared__ __align__(16) _Float16 sAh[BM * 32];
    __shared__ __align__(16) _Float16 sAl[BM * 32];
    __shared__ __align__(16) _Float16 sBh[BN * 32];
    __shared__ __align__(16) _Float16 sBl[BN * 32];
    __shared__ unsigned long long redk[BM];

    const int tid = threadIdx.x;
    const int w = tid >> 6, lane = tid & 63;
    const int quad = lane >> 4, lq = lane & 15;
    const int rb = blockIdx.x / NCHUNKS, chunk = blockIdx.x % NCHUNKS;
    const int row0 = rb * BM;
    const int wmb = (w & 1) * 4, wnb = (w >> 1) * 4;  // 16-row block indices
    const int wm = wmb * 16, wn = wnb * 16;
    const int tstart = chunk * NTILES / NCHUNKS;
    const int tend = (chunk + 1) * NTILES / NCHUNKS;

    if (tid < BM) redk[tid] = 0ull;  // barriers intervene before use

    // runtime layout probe: c1 slot value = logical m, c2 = logical n
    union PF { f16x8 v; _Float16 s[8]; } fidx, fone;
#pragma unroll
    for (int j = 0; j < 8; j++) { fidx.s[j] = (_Float16)0.0f; fone.s[j] = (_Float16)0.0f; }
    if (quad == 0) { fidx.s[0] = (_Float16)(float)lq; fone.s[0] = (_Float16)1.0f; }
    floatx4 c1 = {0.f, 0.f, 0.f, 0.f}, c2 = {0.f, 0.f, 0.f, 0.f};
    c1 = __builtin_amdgcn_mfma_f32_16x16x32_f16(fidx.v, fone.v, c1, 0, 0, 0);
    c2 = __builtin_amdgcn_mfma_f32_16x16x32_f16(fone.v, fidx.v, c2, 0, 0, 0);
    int m_of[4], n_of[4];
#pragma unroll
    for (int r = 0; r < 4; r++) {
        m_of[r] = (int)(c1[r] + 0.5f);
        n_of[r] = (int)(c2[r] + 0.5f);
    }

    // wave -> plane assignment for staging (wave-uniform)
    const _Float16* gbase = (w == 0) ? (Ah + (size_t)row0 * DIM)
                        : (w == 1) ? (Al + (size_t)row0 * DIM)
                        : (w == 2) ? Bh : Bl;  // B base gets +n0*DIM per tile
    _Float16* ldst = (w == 0) ? sAh : (w == 1) ? sAl : (w == 2) ? sBh : sBl;
    // lane l sources row (l&15), k-piece (l>>4) of each 16-row block so the
    // linear LDS write lands piece-major
    const size_t g_lane = (size_t)(lane & 15) * DIM + (size_t)(lane >> 4) * 8;
    const int loff = quad * 128 + lq * 8;  // piece-major intra-block offset
    const bool isB = (w >= 2);

    float rmax[16];
    int ridx[16];
#pragma unroll
    for (int i = 0; i < 16; i++) { rmax[i] = -3.4e38f; ridx[i] = 0; }

    for (int t = tstart; t < tend; ++t) {
        const int n0 = t * BN;
        const _Float16* gsrc = gbase + (isB ? (size_t)t * BN * DIM : 0) + g_lane;
        floatx4 acc[4][4];
#pragma unroll
        for (int mi = 0; mi < 4; mi++)
#pragma unroll
            for (int ni = 0; ni < 4; ni++)
#pragma unroll
                for (int r = 0; r < 4; r++) acc[mi][ni][r] = 0.0f;

        for (int kt = 0; kt < DIM / 32; ++kt) {
            const int k0 = kt * 32;
            __syncthreads();  // previous step's LDS reads complete
            // each wave stages one full plane: 8 blocks of 16 rows x 32 f16
#pragma unroll
            for (int c = 0; c < 8; c++)
                load_lds16(gsrc + (size_t)(c * 16) * DIM + k0, ldst + c * 512);
            __syncthreads();  // staged data visible (compiler drains vmcnt)

            f16x8 ahf[4], alf[4];
#pragma unroll
            for (int i = 0; i < 4; i++) {
                ahf[i] = *(const f16x8*)(&sAh[(wmb + i) * 512 + loff]);
                alf[i] = *(const f16x8*)(&sAl[(wmb + i) * 512 + loff]);
            }
#pragma unroll
            for (int ni = 0; ni < 4; ni++) {
                f16x8 bh = *(const f16x8*)(&sBh[(wnb + ni) * 512 + loff]);
                f16x8 bl = *(const f16x8*)(&sBl[(wnb + ni) * 512 + loff]);
#pragma unroll
                for (int mi = 0; mi < 4; mi++) {
                    acc[mi][ni] = __builtin_amdgcn_mfma_f32_16x16x32_f16(
                        ahf[mi], bh, acc[mi][ni], 0, 0, 0);
                    acc[mi][ni] = __builtin_amdgcn_mfma_f32_16x16x32_f16(
                        ahf[mi], bl, acc[mi][ni], 0, 0, 0);
                    acc[mi][ni] = __builtin_amdgcn_mfma_f32_16x16x32_f16(
                        alf[mi], bh, acc[mi][ni], 0, 0, 0);
                }
            }
        }
        // fold this n-tile into per-row running argmax (probed layout)
#pragma unroll
        for (int mi = 0; mi < 4; mi++)
#pragma unroll
            for (int ni = 0; ni < 4; ni++)
#pragma unroll
                for (int r = 0; r < 4; r++) {
                    float v = acc[mi][ni][r];
                    int col = n0 + wn + ni * 16 + n_of[r];
                    int s = mi * 4 + r;
                    if (v > rmax[s] || (v == rmax[s] && col < ridx[s])) {
                        rmax[s] = v;
                        ridx[s] = col;
                    }
                }
    }

    // reduce: LDS atomicMax keyed by probed row, then one global atomic per row
#pragma unroll
    for (int s = 0; s < 16; ++s) {
        int mi = s >> 2, r = s & 3;
        int rowl = wm + mi * 16 + m_of[r];
        union { float f; uint32_t i; } u;
        u.f = rmax[s];
        uint32_t ord = (u.i & 0x80000000u) ? ~u.i : (u.i | 0x80000000u);
        unsigned long long key =
            ((unsigned long long)ord << 32) | (uint32_t)(~(uint32_t)ridx[s]);
        atomicMax(&redk[rowl], key);
    }
    __syncthreads();
    if (tid < BM) atomicMax(&keys[row0 + tid], redk[tid]);
}

// ================== fallback path (verified): in-kernel split ==================
#define BKF 64
#define LDKF 72
#define TILES_PER_WGF 10
#define NCHUNKSF 25

__global__ __launch_bounds__(256, 2) void gemm_argmax_fused(
    const float* __restrict__ emb, const float* __restrict__ noi,
    const float* __restrict__ table, unsigned long long* __restrict__ keys) {
    __shared__ __align__(16) _Float16 Ah[BM * LDKF];
    __shared__ __align__(16) _Float16 Al[BM * LDKF];
    __shared__ __align__(16) _Float16 Bh[BN * LDKF];
    __shared__ __align__(16) _Float16 Bl[BN * LDKF];
    __shared__ unsigned long long redk[BM];

    const int tid = threadIdx.x;
    const int wave = tid >> 6, lane = tid & 63;
    const int quad = lane >> 4, lq = lane & 15;
    const int rb = blockIdx.x / NCHUNKSF, chunk = blockIdx.x % NCHUNKSF;
    const int row0 = rb * BM;
    const int wm = (wave & 1) * 64, wn = (wave >> 1) * 64;

    if (tid < BM) redk[tid] = 0ull;

    union PF { f16x8 v; _Float16 s[8]; } fidx, fone;
#pragma unroll
    for (int j = 0; j < 8; j++) { fidx.s[j] = (_Float16)0.0f; fone.s[j] = (_Float16)0.0f; }
    if (quad == 0) { fidx.s[0] = (_Float16)(float)lq; fone.s[0] = (_Float16)1.0f; }
    floatx4 c1 = {0.f, 0.f, 0.f, 0.f}, c2 = {0.f, 0.f, 0.f, 0.f};
    c1 = __builtin_amdgcn_mfma_f32_16x16x32_f16(fidx.v, fone.v, c1, 0, 0, 0);
    c2 = __builtin_amdgcn_mfma_f32_16x16x32_f16(fone.v, fidx.v, c2, 0, 0, 0);
    int m_of[4], n_of[4];
#pragma unroll
    for (int r = 0; r < 4; r++) {
        m_of[r] = (int)(c1[r] + 0.5f);
        n_of[r] = (int)(c2[r] + 0.5f);
    }

    float rmax[16];
    int ridx[16];
#pragma unroll
    for (int i = 0; i < 16; i++) { rmax[i] = -3.4e38f; ridx[i] = 0; }

    for (int t = 0; t < TILES_PER_WGF; ++t) {
        const int n0 = (chunk * TILES_PER_WGF + t) * BN;
        floatx4 acc[4][4];
#pragma unroll
        for (int mi = 0; mi < 4; mi++)
#pragma unroll
            for (int ni = 0; ni < 4; ni++)
#pragma unroll
                for (int r = 0; r < 4; r++) acc[mi][ni][r] = 0.0f;

        for (int kt = 0; kt < DIM / BKF; ++kt) {
            const int k0 = kt * BKF;
            __syncthreads();
#pragma unroll
            for (int i = 0; i < 8; i++) {
                int c = i * 256 + tid;
                int r = c >> 4, q = c & 15;
                floatx4 e = *(const floatx4*)(emb + (size_t)(row0 + r) * DIM + k0 + q * 4);
                floatx4 n = *(const floatx4*)(noi + (size_t)(row0 + r) * DIM + k0 + q * 4);
                floatx4 b = *(const floatx4*)(table + (size_t)(n0 + r) * DIM + k0 + q * 4);
                f16x4 ah, al, bh, bl;
#pragma unroll
                for (int j = 0; j < 4; j++) {
                    float pa = (e[j] + n[j]) * SCALE;
                    _Float16 h = (_Float16)pa;
                    ah[j] = h;
                    al[j] = (_Float16)(pa - (float)h);
                    float pb = b[j] * SCALE;
                    _Float16 hb = (_Float16)pb;
                    bh[j] = hb;
                    bl[j] = (_Float16)(pb - (float)hb);
                }
                *(f16x4*)(Ah + r * LDKF + q * 4) = ah;
                *(f16x4*)(Al + r * LDKF + q * 4) = al;
                *(f16x4*)(Bh + r * LDKF + q * 4) = bh;
                *(f16x4*)(Bl + r * LDKF + q * 4) = bl;
            }
            __syncthreads();
#pragma unroll
            for (int ks = 0; ks < BKF; ks += 32) {
                f16x8 bhf[4], blf[4], ahf[4], alf[4];
#pragma unroll
                for (int i = 0; i < 4; i++) {
                    bhf[i] = *(const f16x8*)(Bh + (wn + i * 16 + lq) * LDKF + ks + quad * 8);
                    blf[i] = *(const f16x8*)(Bl + (wn + i * 16 + lq) * LDKF + ks + quad * 8);
                    ahf[i] = *(const f16x8*)(Ah + (wm + i * 16 + lq) * LDKF + ks + quad * 8);
                    alf[i] = *(const f16x8*)(Al + (wm + i * 16 + lq) * LDKF + ks + quad * 8);
                }
#pragma unroll
                for (int mi = 0; mi < 4; mi++)
#pragma unroll
                    for (int ni = 0; ni < 4; ni++) {
                        acc[mi][ni] = __builtin_amdgcn_mfma_f32_16x16x32_f16(
                            ahf[mi], bhf[ni], acc[mi][ni], 0, 0, 0);
                        acc[mi][ni] = __builtin_amdgcn_mfma_f32_16x16x32_f16(
                            ahf[mi], blf[ni], acc[mi][ni], 0, 0, 0);
                        acc[mi][ni] = __builtin_amdgcn_mfma_f32_16x16x32_f16(
                            alf[mi], bhf[ni], acc[mi][ni], 0, 0, 0);
                    }
            }
        }
#pragma unroll
        for (int mi = 0; mi < 4; mi++)
#pragma unroll
            for (int ni = 0; ni < 4; ni++)
#pragma unroll
                for (int r = 0; r < 4; r++) {
                    float v = acc[mi][ni][r];
                    int col = n0 + wn + ni * 16 + n_of[r];
                    int s = mi * 4 + r;
                    if (v > rmax[s] || (v == rmax[s] && col < ridx[s])) {
                        rmax[s] = v;
                        ridx[s] = col;
                    }
                }
    }

#pragma unroll
    for (int s = 0; s < 16; ++s) {
        int mi = s >> 2, r = s & 3;
        int rowl = wm + mi * 16 + m_of[r];
        union { float f; uint32_t i; } u;
        u.f = rmax[s];
        uint32_t ord = (u.i & 0x80000000u) ? ~u.i : (u.i | 0x80000000u);
        unsigned long long key =
            ((unsigned long long)ord << 32) | (uint32_t)(~(uint32_t)ridx[s]);
        atomicMax(&redk[rowl], key);
    }
    __syncthreads();
    if (tid < BM) atomicMax(&keys[row0 + tid], redk[tid]);
}

// ---- gather winning table rows (f32) to output ----
__global__ void gather_kernel(const unsigned long long* __restrict__ keys,
                              const float* __restrict__ table,
                              float* __restrict__ out) {
    int row = blockIdx.x;
    unsigned long long key = keys[row];
    uint32_t ix = ~(uint32_t)(key & 0xFFFFFFFFull);
    const floatx4* src = (const floatx4*)(table + (size_t)ix * DIM);
    floatx4* dst = (floatx4*)(out + (size_t)row * DIM);
    dst[threadIdx.x] = src[threadIdx.x];  // 256 * 16B = 4 KB row
}

extern "C" void kernel_launch(void* const* d_in, const int* in_sizes, int n_in,
                              void* d_out, int out_size, void* d_ws, size_t ws_size,
                              hipStream_t stream) {
    (void)in_sizes; (void)n_in; (void)out_size;
    const float* emb = (const float*)d_in[0];
    const float* table = (const float*)d_in[1];
    const float* noi = (const float*)d_in[2];
    float* out = (float*)d_out;

    uint8_t* ws = (uint8_t*)d_ws;
    unsigned long long* keys = (unsigned long long*)ws;
    const size_t keysB = (size_t)ROWS * 8;
    const size_t aB = (size_t)ROWS * DIM * 2;    // 8.39 MB per A plane
    const size_t bB = (size_t)VOCAB * DIM * 2;   // 65.5 MB per B plane
    const size_t need = keysB + 2 * aB + 2 * bB; // ~141 MB

    if (ws_size >= need) {
        _Float16* Ah = (_Float16*)(ws + keysB);
        _Float16* Al = (_Float16*)(ws + keysB + aB);
        _Float16* Bh = (_Float16*)(ws + keysB + 2 * aB);
        _Float16* Bl = (_Float16*)(ws + keysB + 2 * aB + bB);
        const int ablk = ROWS * DIM / 8 / 256;       // 2048
        const int bblk = VOCAB * DIM / 8 / 256;      // 16000
        prep<<<ablk + bblk, 256, 0, stream>>>(emb, noi, table, Ah, Al, Bh, Bl, keys);
        gemm_argmax_pre<<<(ROWS / BM) * NCHUNKS, 256, 0, stream>>>(Ah, Al, Bh, Bl, keys);
    } else {
        init_keys<<<ROWS / 256, 256, 0, stream>>>(keys);
        gemm_argmax_fused<<<(ROWS / BM) * NCHUNKSF, 256, 0, stream>>>(emb, noi, table, keys);
    }
    gather_kernel<<<ROWS, 256, 0, stream>>>(keys, table, out);
}

// Round 5
// 1043.962 us; speedup vs baseline: 1.5481x; 1.2382x over previous
//
#include <hip/hip_runtime.h>
#include <stdint.h>

#define ROWS 4096
#define DIM 1024
#define VOCAB 32000
#define BM 128
#define BN 128
#define NTILES (VOCAB / BN)  // 250
#define NCHUNKS 24           // 32 row-blocks * 24 = 768 blocks = 3/CU co-resident
                             // (R3: 4/CU never materializes; R1: 2/CU starves TLP)
#define SCALE 2048.0f        // keeps f16 lo-plane normal; argmax is scale-invariant

typedef float floatx4 __attribute__((ext_vector_type(4)));
typedef _Float16 f16x8 __attribute__((ext_vector_type(8)));
typedef _Float16 f16x4 __attribute__((ext_vector_type(4)));

__device__ __forceinline__ void load_lds16(const _Float16* g, _Float16* l) {
    __builtin_amdgcn_global_load_lds(
        (const __attribute__((address_space(1))) uint32_t*)g,
        (__attribute__((address_space(3))) uint32_t*)l, 16, 0, 0);
}

// ---- kernel 0 (fallback path only): zero the per-row argmax keys ----
__global__ void init_keys(unsigned long long* __restrict__ keys) {
    int i = blockIdx.x * 256 + threadIdx.x;
    if (i < ROWS) keys[i] = 0ull;
}

// ---- fused prep: keys init + A=emb+noise split + B=table split (f16 hi/lo planes) ----
__global__ void prep(const float* __restrict__ emb, const float* __restrict__ noi,
                     const float* __restrict__ table,
                     _Float16* __restrict__ Ah, _Float16* __restrict__ Al,
                     _Float16* __restrict__ Bh, _Float16* __restrict__ Bl,
                     unsigned long long* __restrict__ keys) {
    const int bid = blockIdx.x;
    const int ABLK = ROWS * DIM / 8 / 256;  // 2048
    if (bid < ABLK) {
        if (bid < ROWS / 256) keys[bid * 256 + threadIdx.x] = 0ull;
        size_t i = ((size_t)bid * 256 + threadIdx.x) * 8;
        floatx4 a = *(const floatx4*)(emb + i);
        floatx4 b = *(const floatx4*)(emb + i + 4);
        floatx4 c = *(const floatx4*)(noi + i);
        floatx4 d = *(const floatx4*)(noi + i + 4);
        f16x8 h, l;
#pragma unroll
        for (int j = 0; j < 4; j++) {
            float p = (a[j] + c[j]) * SCALE;
            _Float16 hh = (_Float16)p;
            h[j] = hh; l[j] = (_Float16)(p - (float)hh);
            float q = (b[j] + d[j]) * SCALE;
            _Float16 hq = (_Float16)q;
            h[4 + j] = hq; l[4 + j] = (_Float16)(q - (float)hq);
        }
        *(f16x8*)(Ah + i) = h;
        *(f16x8*)(Al + i) = l;
    } else {
        size_t i = ((size_t)(bid - ABLK) * 256 + threadIdx.x) * 8;
        floatx4 a = *(const floatx4*)(table + i);
        floatx4 b = *(const floatx4*)(table + i + 4);
        f16x8 h, l;
#pragma unroll
        for (int j = 0; j < 4; j++) {
            float p = a[j] * SCALE;
            _Float16 hh = (_Float16)p;
            h[j] = hh; l[j] = (_Float16)(p - (float)hh);
            float q = b[j] * SCALE;
            _Float16 hq = (_Float16)q;
            h[4 + j] = hq; l[4 + j] = (_Float16)(q - (float)hq);
        }
        *(f16x8*)(Bh + i) = h;
        *(f16x8*)(Bl + i) = l;
    }
}

// ---- main GEMM+argmax: R0's schedule/occupancy (grid 768 = 3/CU,      ----
// ---- single-buffer, lb(256,3)) + XOR-swizzled coalescing-preserving   ----
// ---- LDS layout.                                                      ----
// grid = 32 * NCHUNKS = 768; block = 256 (4 waves, 2x2 wave grid). BK=32.
//
// Coalescing vs bank-conflict resolution (R0 vs R4 lesson):
//  * R0: lane l fetched row=(l>>2), piece=(l&3): 4 adjacent lanes per 64B
//    line (good VMEM merge) but row-major LDS -> 6.85e7 bank conflicts.
//  * R4: piece-major fetch row=(l&15), piece=(l>>4): conflict-free LDS but
//    adjacent lanes 2KB apart -> ~4x VMEM requests -> MfmaUtil 49->29%.
//  * Now: keep R0's row=(l>>2) (adjacent-lane 64B merge preserved) and XOR
//    only the within-line piece order: piece = (l&3)^((l>>3)&3). LDS slot s
//    (16B units, linear lane write) holds row=(s>>2), piece=(s&3)^((s>>3)&3).
//    Fragment read for (quad,lq): slot = lq*4 + (quad^((lq>>1)&3)) -> each
//    consecutive 8-lane phase hits 8 distinct bank groups {0,4,1,5,2,6,3,7}
//    -> conflict-free. Same involution on both sides (write source & read).
//
// __launch_bounds__(256,3): ~84 VGPR, no spill. Do NOT use min-waves=4
// (R2: forces 64-VGPR tier, spills accumulators, WRITE_SIZE -> 1.18 GB).
// Do NOT exceed 3 blocks/CU of grid pressure (R3: 4th block not resident).
__global__ __launch_bounds__(256, 3) void gemm_argmax_pre(
    const _Float16* __restrict__ Ah, const _Float16* __restrict__ Al,
    const _Float16* __restrict__ Bh, const _Float16* __restrict__ Bl,
    unsigned long long* __restrict__ keys) {
    __shared__ __align__(16) _Float16 sAh[BM * 32];
    __shared__ __align__(16) _Float16 sAl[BM * 32];
    __shared__ __align__(16) _Float16 sBh[BN * 32];
    __shared__ __align__(16) _Float16 sBl[BN * 32];
    __shared__ unsigned long long redk[BM];

    const int tid = threadIdx.x;
    const int w = tid >> 6, lane = tid & 63;
    const int quad = lane >> 4, lq = lane & 15;
    const int rb = blockIdx.x / NCHUNKS, chunk = blockIdx.x % NCHUNKS;
    const int row0 = rb * BM;
    const int wmb = (w & 1) * 4, wnb = (w >> 1) * 4;  // 16-row block indices
    const int wm = wmb * 16, wn = wnb * 16;
    const int tstart = chunk * NTILES / NCHUNKS;
    const int tend = (chunk + 1) * NTILES / NCHUNKS;

    if (tid < BM) redk[tid] = 0ull;  // barriers intervene before use

    // runtime layout probe: c1 slot value = logical m, c2 = logical n
    union PF { f16x8 v; _Float16 s[8]; } fidx, fone;
#pragma unroll
    for (int j = 0; j < 8; j++) { fidx.s[j] = (_Float16)0.0f; fone.s[j] = (_Float16)0.0f; }
    if (quad == 0) { fidx.s[0] = (_Float16)(float)lq; fone.s[0] = (_Float16)1.0f; }
    floatx4 c1 = {0.f, 0.f, 0.f, 0.f}, c2 = {0.f, 0.f, 0.f, 0.f};
    c1 = __builtin_amdgcn_mfma_f32_16x16x32_f16(fidx.v, fone.v, c1, 0, 0, 0);
    c2 = __builtin_amdgcn_mfma_f32_16x16x32_f16(fone.v, fidx.v, c2, 0, 0, 0);
    int m_of[4], n_of[4];
#pragma unroll
    for (int r = 0; r < 4; r++) {
        m_of[r] = (int)(c1[r] + 0.5f);
        n_of[r] = (int)(c2[r] + 0.5f);
    }

    // wave -> plane assignment for staging (wave-uniform)
    const _Float16* gbase = (w == 0) ? (Ah + (size_t)row0 * DIM)
                        : (w == 1) ? (Al + (size_t)row0 * DIM)
                        : (w == 2) ? Bh : Bl;  // B base gets +n0*DIM per tile
    _Float16* ldst = (w == 0) ? sAh : (w == 1) ? sAl : (w == 2) ? sBh : sBl;
    // lane l sources row (l>>2) [R0's coalesced mapping], swizzled piece
    const int piece = (lane & 3) ^ ((lane >> 3) & 3);
    const size_t g_lane = (size_t)(lane >> 2) * DIM + (size_t)piece * 8;
    // matching swizzled fragment-read offset (f16 elements within 512-elem block)
    const int rdo = lq * 32 + (quad ^ ((lq >> 1) & 3)) * 8;
    const bool isB = (w >= 2);

    float rmax[16];
    int ridx[16];
#pragma unroll
    for (int i = 0; i < 16; i++) { rmax[i] = -3.4e38f; ridx[i] = 0; }

    for (int t = tstart; t < tend; ++t) {
        const int n0 = t * BN;
        const _Float16* gsrc = gbase + (isB ? (size_t)t * BN * DIM : 0) + g_lane;
        floatx4 acc[4][4];
#pragma unroll
        for (int mi = 0; mi < 4; mi++)
#pragma unroll
            for (int ni = 0; ni < 4; ni++)
#pragma unroll
                for (int r = 0; r < 4; r++) acc[mi][ni][r] = 0.0f;

        for (int kt = 0; kt < DIM / 32; ++kt) {
            const int k0 = kt * 32;
            __syncthreads();  // previous step's LDS reads complete
            // each wave stages one full plane: 8 blocks of 16 rows x 32 f16
#pragma unroll
            for (int c = 0; c < 8; c++)
                load_lds16(gsrc + (size_t)(c * 16) * DIM + k0, ldst + c * 512);
            __syncthreads();  // staged data visible (compiler drains vmcnt)

            f16x8 ahf[4], alf[4];
#pragma unroll
            for (int i = 0; i < 4; i++) {
                ahf[i] = *(const f16x8*)(&sAh[(wmb + i) * 512 + rdo]);
                alf[i] = *(const f16x8*)(&sAl[(wmb + i) * 512 + rdo]);
            }
#pragma unroll
            for (int ni = 0; ni < 4; ni++) {
                f16x8 bh = *(const f16x8*)(&sBh[(wnb + ni) * 512 + rdo]);
                f16x8 bl = *(const f16x8*)(&sBl[(wnb + ni) * 512 + rdo]);
#pragma unroll
                for (int mi = 0; mi < 4; mi++) {
                    acc[mi][ni] = __builtin_amdgcn_mfma_f32_16x16x32_f16(
                        ahf[mi], bh, acc[mi][ni], 0, 0, 0);
                    acc[mi][ni] = __builtin_amdgcn_mfma_f32_16x16x32_f16(
                        ahf[mi], bl, acc[mi][ni], 0, 0, 0);
                    acc[mi][ni] = __builtin_amdgcn_mfma_f32_16x16x32_f16(
                        alf[mi], bh, acc[mi][ni], 0, 0, 0);
                }
            }
        }
        // fold this n-tile into per-row running argmax (probed layout)
#pragma unroll
        for (int mi = 0; mi < 4; mi++)
#pragma unroll
            for (int ni = 0; ni < 4; ni++)
#pragma unroll
                for (int r = 0; r < 4; r++) {
                    float v = acc[mi][ni][r];
                    int col = n0 + wn + ni * 16 + n_of[r];
                    int s = mi * 4 + r;
                    if (v > rmax[s] || (v == rmax[s] && col < ridx[s])) {
                        rmax[s] = v;
                        ridx[s] = col;
                    }
                }
    }

    // reduce: LDS atomicMax keyed by probed row, then one global atomic per row
#pragma unroll
    for (int s = 0; s < 16; ++s) {
        int mi = s >> 2, r = s & 3;
        int rowl = wm + mi * 16 + m_of[r];
        union { float f; uint32_t i; } u;
        u.f = rmax[s];
        uint32_t ord = (u.i & 0x80000000u) ? ~u.i : (u.i | 0x80000000u);
        unsigned long long key =
            ((unsigned long long)ord << 32) | (uint32_t)(~(uint32_t)ridx[s]);
        atomicMax(&redk[rowl], key);
    }
    __syncthreads();
    if (tid < BM) atomicMax(&keys[row0 + tid], redk[tid]);
}

// ================== fallback path (verified): in-kernel split ==================
#define BKF 64
#define LDKF 72
#define TILES_PER_WGF 10
#define NCHUNKSF 25

__global__ __launch_bounds__(256, 2) void gemm_argmax_fused(
    const float* __restrict__ emb, const float* __restrict__ noi,
    const float* __restrict__ table, unsigned long long* __restrict__ keys) {
    __shared__ __align__(16) _Float16 Ah[BM * LDKF];
    __shared__ __align__(16) _Float16 Al[BM * LDKF];
    __shared__ __align__(16) _Float16 Bh[BN * LDKF];
    __shared__ __align__(16) _Float16 Bl[BN * LDKF];
    __shared__ unsigned long long redk[BM];

    const int tid = threadIdx.x;
    const int wave = tid >> 6, lane = tid & 63;
    const int quad = lane >> 4, lq = lane & 15;
    const int rb = blockIdx.x / NCHUNKSF, chunk = blockIdx.x % NCHUNKSF;
    const int row0 = rb * BM;
    const int wm = (wave & 1) * 64, wn = (wave >> 1) * 64;

    if (tid < BM) redk[tid] = 0ull;

    union PF { f16x8 v; _Float16 s[8]; } fidx, fone;
#pragma unroll
    for (int j = 0; j < 8; j++) { fidx.s[j] = (_Float16)0.0f; fone.s[j] = (_Float16)0.0f; }
    if (quad == 0) { fidx.s[0] = (_Float16)(float)lq; fone.s[0] = (_Float16)1.0f; }
    floatx4 c1 = {0.f, 0.f, 0.f, 0.f}, c2 = {0.f, 0.f, 0.f, 0.f};
    c1 = __builtin_amdgcn_mfma_f32_16x16x32_f16(fidx.v, fone.v, c1, 0, 0, 0);
    c2 = __builtin_amdgcn_mfma_f32_16x16x32_f16(fone.v, fidx.v, c2, 0, 0, 0);
    int m_of[4], n_of[4];
#pragma unroll
    for (int r = 0; r < 4; r++) {
        m_of[r] = (int)(c1[r] + 0.5f);
        n_of[r] = (int)(c2[r] + 0.5f);
    }

    float rmax[16];
    int ridx[16];
#pragma unroll
    for (int i = 0; i < 16; i++) { rmax[i] = -3.4e38f; ridx[i] = 0; }

    for (int t = 0; t < TILES_PER_WGF; ++t) {
        const int n0 = (chunk * TILES_PER_WGF + t) * BN;
        floatx4 acc[4][4];
#pragma unroll
        for (int mi = 0; mi < 4; mi++)
#pragma unroll
            for (int ni = 0; ni < 4; ni++)
#pragma unroll
                for (int r = 0; r < 4; r++) acc[mi][ni][r] = 0.0f;

        for (int kt = 0; kt < DIM / BKF; ++kt) {
            const int k0 = kt * BKF;
            __syncthreads();
#pragma unroll
            for (int i = 0; i < 8; i++) {
                int c = i * 256 + tid;
                int r = c >> 4, q = c & 15;
                floatx4 e = *(const floatx4*)(emb + (size_t)(row0 + r) * DIM + k0 + q * 4);
                floatx4 n = *(const floatx4*)(noi + (size_t)(row0 + r) * DIM + k0 + q * 4);
                floatx4 b = *(const floatx4*)(table + (size_t)(n0 + r) * DIM + k0 + q * 4);
                f16x4 ah, al, bh, bl;
#pragma unroll
                for (int j = 0; j < 4; j++) {
                    float pa = (e[j] + n[j]) * SCALE;
                    _Float16 h = (_Float16)pa;
                    ah[j] = h;
                    al[j] = (_Float16)(pa - (float)h);
                    float pb = b[j] * SCALE;
                    _Float16 hb = (_Float16)pb;
                    bh[j] = hb;
                    bl[j] = (_Float16)(pb - (float)hb);
                }
                *(f16x4*)(Ah + r * LDKF + q * 4) = ah;
                *(f16x4*)(Al + r * LDKF + q * 4) = al;
                *(f16x4*)(Bh + r * LDKF + q * 4) = bh;
                *(f16x4*)(Bl + r * LDKF + q * 4) = bl;
            }
            __syncthreads();
#pragma unroll
            for (int ks = 0; ks < BKF; ks += 32) {
                f16x8 bhf[4], blf[4], ahf[4], alf[4];
#pragma unroll
                for (int i = 0; i < 4; i++) {
                    bhf[i] = *(const f16x8*)(Bh + (wn + i * 16 + lq) * LDKF + ks + quad * 8);
                    blf[i] = *(const f16x8*)(Bl + (wn + i * 16 + lq) * LDKF + ks + quad * 8);
                    ahf[i] = *(const f16x8*)(Ah + (wm + i * 16 + lq) * LDKF + ks + quad * 8);
                    alf[i] = *(const f16x8*)(Al + (wm + i * 16 + lq) * LDKF + ks + quad * 8);
                }
#pragma unroll
                for (int mi = 0; mi < 4; mi++)
#pragma unroll
                    for (int ni = 0; ni < 4; ni++) {
                        acc[mi][ni] = __builtin_amdgcn_mfma_f32_16x16x32_f16(
                            ahf[mi], bhf[ni], acc[mi][ni], 0, 0, 0);
                        acc[mi][ni] = __builtin_amdgcn_mfma_f32_16x16x32_f16(
                            ahf[mi], blf[ni], acc[mi][ni], 0, 0, 0);
                        acc[mi][ni] = __builtin_amdgcn_mfma_f32_16x16x32_f16(
                            alf[mi], bhf[ni], acc[mi][ni], 0, 0, 0);
                    }
            }
        }
#pragma unroll
        for (int mi = 0; mi < 4; mi++)
#pragma unroll
            for (int ni = 0; ni < 4; ni++)
#pragma unroll
                for (int r = 0; r < 4; r++) {
                    float v = acc[mi][ni][r];
                    int col = n0 + wn + ni * 16 + n_of[r];
                    int s = mi * 4 + r;
                    if (v > rmax[s] || (v == rmax[s] && col < ridx[s])) {
                        rmax[s] = v;
                        ridx[s] = col;
                    }
                }
    }

#pragma unroll
    for (int s = 0; s < 16; ++s) {
        int mi = s >> 2, r = s & 3;
        int rowl = wm + mi * 16 + m_of[r];
        union { float f; uint32_t i; } u;
        u.f = rmax[s];
        uint32_t ord = (u.i & 0x80000000u) ? ~u.i : (u.i | 0x80000000u);
        unsigned long long key =
            ((unsigned long long)ord << 32) | (uint32_t)(~(uint32_t)ridx[s]);
        atomicMax(&redk[rowl], key);
    }
    __syncthreads();
    if (tid < BM) atomicMax(&keys[row0 + tid], redk[tid]);
}

// ---- gather winning table rows (f32) to output ----
__global__ void gather_kernel(const unsigned long long* __restrict__ keys,
                              const float* __restrict__ table,
                              float* __restrict__ out) {
    int row = blockIdx.x;
    unsigned long long key = keys[row];
    uint32_t ix = ~(uint32_t)(key & 0xFFFFFFFFull);
    const floatx4* src = (const floatx4*)(table + (size_t)ix * DIM);
    floatx4* dst = (floatx4*)(out + (size_t)row * DIM);
    dst[threadIdx.x] = src[threadIdx.x];  // 256 * 16B = 4 KB row
}

extern "C" void kernel_launch(void* const* d_in, const int* in_sizes, int n_in,
                              void* d_out, int out_size, void* d_ws, size_t ws_size,
                              hipStream_t stream) {
    (void)in_sizes; (void)n_in; (void)out_size;
    const float* emb = (const float*)d_in[0];
    const float* table = (const float*)d_in[1];
    const float* noi = (const float*)d_in[2];
    float* out = (float*)d_out;

    uint8_t* ws = (uint8_t*)d_ws;
    unsigned long long* keys = (unsigned long long*)ws;
    const size_t keysB = (size_t)ROWS * 8;
    const size_t aB = (size_t)ROWS * DIM * 2;    // 8.39 MB per A plane
    const size_t bB = (size_t)VOCAB * DIM * 2;   // 65.5 MB per B plane
    const size_t need = keysB + 2 * aB + 2 * bB; // ~141 MB

    if (ws_size >= need) {
        _Float16* Ah = (_Float16*)(ws + keysB);
        _Float16* Al = (_Float16*)(ws + keysB + aB);
        _Float16* Bh = (_Float16*)(ws + keysB + 2 * aB);
        _Float16* Bl = (_Float16*)(ws + keysB + 2 * aB + bB);
        const int ablk = ROWS * DIM / 8 / 256;       // 2048
        const int bblk = VOCAB * DIM / 8 / 256;      // 16000
        prep<<<ablk + bblk, 256, 0, stream>>>(emb, noi, table, Ah, Al, Bh, Bl, keys);
        gemm_argmax_pre<<<(ROWS / BM) * NCHUNKS, 256, 0, stream>>>(Ah, Al, Bh, Bl, keys);
    } else {
        init_keys<<<ROWS / 256, 256, 0, stream>>>(keys);
        gemm_argmax_fused<<<(ROWS / BM) * NCHUNKSF, 256, 0, stream>>>(emb, noi, table, keys);
    }
    gather_kernel<<<ROWS, 256, 0, stream>>>(keys, table, out);
}